// Round 3
// baseline (20.038 us; speedup 1.0000x reference)
//
#include <hip/hip_runtime.h>
#include <hip/hip_bf16.h>

// Shapes (fixed by the reference)
constexpr int IN_F  = 1024;
constexpr int OUT_F = 1024;
constexpr int LAT   = 16;
constexpr int BATCH = 256;

typedef __attribute__((ext_vector_type(8))) short  bf16x8;  // 8 bf16 (4 VGPRs)
typedef __attribute__((ext_vector_type(4))) float  f32x4;   // MFMA accumulator

static __device__ __forceinline__ unsigned short bf16_bits(float v) {
  __hip_bfloat16 h = __float2bfloat16(v);
  return *reinterpret_cast<unsigned short*>(&h);
}

// ---------------------------------------------------------------------------
// Kernel 1 (slim prep): s = z @ lt_w^T + lt_b; xs = bf16(x*s); ss = bf16(s*s)
// grid = 256 blocks (one per batch row), 256 threads, 4 elements/thread.
// ---------------------------------------------------------------------------
__global__ __launch_bounds__(256) void prep_a(
    const float* __restrict__ tensor, const float* __restrict__ z,
    const float* __restrict__ lt_w, const float* __restrict__ lt_b,
    __hip_bfloat16* __restrict__ xs, __hip_bfloat16* __restrict__ ss) {
  const int b = blockIdx.x;
  const int t = threadIdx.x;
  float zr[LAT];
  const float4* z4 = reinterpret_cast<const float4*>(z + b * LAT);
#pragma unroll
  for (int j = 0; j < LAT / 4; ++j) {
    float4 v = z4[j];
    zr[4 * j + 0] = v.x; zr[4 * j + 1] = v.y;
    zr[4 * j + 2] = v.z; zr[4 * j + 3] = v.w;
  }
  const int i0 = t * 4;  // 256 threads x 4 elements = 1024
  float s[4];
#pragma unroll
  for (int j = 0; j < 4; ++j) {
    const float4* lw = reinterpret_cast<const float4*>(lt_w + (i0 + j) * LAT);
    float acc = lt_b[i0 + j];
#pragma unroll
    for (int q = 0; q < LAT / 4; ++q) {
      float4 v = lw[q];
      acc += zr[4 * q + 0] * v.x + zr[4 * q + 1] * v.y +
             zr[4 * q + 2] * v.z + zr[4 * q + 3] * v.w;
    }
    s[j] = acc;
  }
  const float4 x = *reinterpret_cast<const float4*>(tensor + b * IN_F + i0);
  union { unsigned short u[4]; uint2 v; } pxs, pss;
  pxs.u[0] = bf16_bits(x.x * s[0]); pss.u[0] = bf16_bits(s[0] * s[0]);
  pxs.u[1] = bf16_bits(x.y * s[1]); pss.u[1] = bf16_bits(s[1] * s[1]);
  pxs.u[2] = bf16_bits(x.z * s[2]); pss.u[2] = bf16_bits(s[2] * s[2]);
  pxs.u[3] = bf16_bits(x.w * s[3]); pss.u[3] = bf16_bits(s[3] * s[3]);
  *reinterpret_cast<uint2*>(xs + b * IN_F + i0) = pxs.v;
  *reinterpret_cast<uint2*>(ss + b * IN_F + i0) = pss.v;
}

// ---------------------------------------------------------------------------
// Kernel 2: fused double-GEMM + demod epilogue; W transposed IN-KERNEL.
//   acc1 = xs @ W, acc2 = ss @ W^2; out = acc1*rsqrt(acc2+1e-8)+bias
// BM=BN=32, BK=64; 256 threads = 4 waves (2x2 of 16x16). grid (32, 8).
// W staging: thread owns column n0+(t&31), k-octet (t>>5): 8 wave-coalesced
// dword loads -> in-reg bf16 convert + square -> 2x ds_write_b128 into the
// same XOR-swizzled [n][k] layout the MFMA reads expect. Double-buffered,
// one barrier per K-iter, next-iter loads issued right after the barrier.
// ---------------------------------------------------------------------------
__global__ __launch_bounds__(256) void gemm_mod(
    const __hip_bfloat16* __restrict__ xs, const __hip_bfloat16* __restrict__ ss,
    const float* __restrict__ W, const float* __restrict__ bias,
    float* __restrict__ out) {
  __shared__ __hip_bfloat16 lds[2][4][32 * 64];  // [buf][xs,ss,wt,w2t]

  const int n0 = blockIdx.x * 32;
  const int m0 = blockIdx.y * 32;
  const int t = threadIdx.x;
  const int lane = t & 63;
  const int wave = t >> 6;
  const int wm = wave >> 1;
  const int wn = wave & 1;

  // A staging map: thread t -> (row = t>>3, 16B chunk c = t&7)
  const int srow = t >> 3;
  const int sc = t & 7;
  const int swz_off = srow * 128 + ((sc ^ (srow & 7)) << 4);
  const int gofs_a = (m0 + srow) * IN_F + sc * 8;

  // W staging map: thread t -> column n_l = t&31, k-octet kr = t>>5
  const int wn_l = t & 31;
  const int wkr = t >> 5;  // 0..7
  const int wswz = wn_l * 128 + ((wkr ^ (wn_l & 7)) << 4);
  const int wg_base = (wkr * 8) * OUT_F + n0 + wn_l;  // add k0*OUT_F per iter

  // fragment addressing (unchanged, proven)
  const int frow = lane & 15;
  const int h = lane >> 4;
  const int arow = wm * 16 + frow;
  const int brow = wn * 16 + frow;
  const int aoff0 = arow * 128 + (((0 + h) ^ (arow & 7)) << 4);
  const int aoff1 = arow * 128 + (((4 + h) ^ (arow & 7)) << 4);
  const int boff0 = brow * 128 + (((0 + h) ^ (brow & 7)) << 4);
  const int boff1 = brow * 128 + (((4 + h) ^ (brow & 7)) << 4);

  f32x4 acc1 = {0.f, 0.f, 0.f, 0.f};
  f32x4 acc2 = {0.f, 0.f, 0.f, 0.f};

  // prologue: K-tile 0 loads
  bf16x8 ra = *reinterpret_cast<const bf16x8*>(xs + gofs_a);
  bf16x8 rb = *reinterpret_cast<const bf16x8*>(ss + gofs_a);
  float wv[8];
#pragma unroll
  for (int j = 0; j < 8; ++j) wv[j] = W[wg_base + j * OUT_F];

#pragma unroll
  for (int tstep = 0; tstep < IN_F / 64; ++tstep) {
    char* l0 = reinterpret_cast<char*>(lds[tstep & 1][0]);
    char* l1 = reinterpret_cast<char*>(lds[tstep & 1][1]);
    char* l2 = reinterpret_cast<char*>(lds[tstep & 1][2]);
    char* l3 = reinterpret_cast<char*>(lds[tstep & 1][3]);
    // convert current W regs (bf16 + squared bf16), then stage everything
    union { unsigned short u[8]; bf16x8 v; } pw, pw2;
#pragma unroll
    for (int j = 0; j < 8; ++j) {
      pw.u[j]  = bf16_bits(wv[j]);
      pw2.u[j] = bf16_bits(wv[j] * wv[j]);
    }
    *reinterpret_cast<bf16x8*>(l0 + swz_off) = ra;
    *reinterpret_cast<bf16x8*>(l1 + swz_off) = rb;
    *reinterpret_cast<bf16x8*>(l2 + wswz) = pw.v;
    *reinterpret_cast<bf16x8*>(l3 + wswz) = pw2.v;
    __syncthreads();
    // issue next tile's global loads (hidden under ds_read + MFMA below)
    if (tstep < IN_F / 64 - 1) {
      const int k0 = (tstep + 1) * 64;
      ra = *reinterpret_cast<const bf16x8*>(xs + gofs_a + k0);
      rb = *reinterpret_cast<const bf16x8*>(ss + gofs_a + k0);
#pragma unroll
      for (int j = 0; j < 8; ++j) wv[j] = W[k0 * OUT_F + wg_base + j * OUT_F];
    }
    // MFMA on current buffer (two K=32 sub-steps)
    bf16x8 a1 = *reinterpret_cast<const bf16x8*>(l0 + aoff0);
    bf16x8 a2 = *reinterpret_cast<const bf16x8*>(l1 + aoff0);
    bf16x8 b1 = *reinterpret_cast<const bf16x8*>(l2 + boff0);
    bf16x8 b2 = *reinterpret_cast<const bf16x8*>(l3 + boff0);
    acc1 = __builtin_amdgcn_mfma_f32_16x16x32_bf16(a1, b1, acc1, 0, 0, 0);
    acc2 = __builtin_amdgcn_mfma_f32_16x16x32_bf16(a2, b2, acc2, 0, 0, 0);
    a1 = *reinterpret_cast<const bf16x8*>(l0 + aoff1);
    a2 = *reinterpret_cast<const bf16x8*>(l1 + aoff1);
    b1 = *reinterpret_cast<const bf16x8*>(l2 + boff1);
    b2 = *reinterpret_cast<const bf16x8*>(l3 + boff1);
    acc1 = __builtin_amdgcn_mfma_f32_16x16x32_bf16(a1, b1, acc1, 0, 0, 0);
    acc2 = __builtin_amdgcn_mfma_f32_16x16x32_bf16(a2, b2, acc2, 0, 0, 0);
  }

  // epilogue: C/D layout is col = lane&15, row = (lane>>4)*4 + reg
  const int col = n0 + wn * 16 + (lane & 15);
  const float bs = bias[col];
#pragma unroll
  for (int q = 0; q < 4; ++q) {
    const int row = m0 + wm * 16 + (lane >> 4) * 4 + q;
    out[row * OUT_F + col] = acc1[q] * __frsqrt_rn(acc2[q] + 1e-8f) + bs;
  }
}

// ---------------------------------------------------------------------------
extern "C" void kernel_launch(void* const* d_in, const int* in_sizes, int n_in,
                              void* d_out, int out_size, void* d_ws, size_t ws_size,
                              hipStream_t stream) {
  const float* tensor = (const float*)d_in[0];  // [256][1024]
  const float* z      = (const float*)d_in[1];  // [256][16]
  const float* W      = (const float*)d_in[2];  // [1024][1024]
  const float* bias   = (const float*)d_in[3];  // [1024]
  const float* lt_w   = (const float*)d_in[4];  // [1024][16]
  const float* lt_b   = (const float*)d_in[5];  // [1024]
  float* out = (float*)d_out;

  // workspace: xs[512K] ss[512K] bf16
  char* ws = (char*)d_ws;
  __hip_bfloat16* xsb = (__hip_bfloat16*)(ws);
  __hip_bfloat16* ssb = (__hip_bfloat16*)(ws + 512 * 1024);

  prep_a<<<BATCH, 256, 0, stream>>>(tensor, z, lt_w, lt_b, xsb, ssb);
  gemm_mod<<<dim3(OUT_F / 32, BATCH / 32), 256, 0, stream>>>(
      xsb, ssb, W, bias, out);
}